// Round 1
// baseline (204.877 us; speedup 1.0000x reference)
//
#include <hip/hip_runtime.h>
#include <hip/hip_bf16.h>
#include <cstdint>

#define L_DIM 4800
#define C_DIM 256
#define CONF_ELEMS ((size_t)2 * L_DIM * L_DIM)

typedef _Float16 f16x8 __attribute__((ext_vector_type(8)));
typedef _Float16 f16x4 __attribute__((ext_vector_type(4)));
typedef float f32x4 __attribute__((ext_vector_type(4)));

// ws layout (bytes):
//   rowsum  f32 [9600]   @ 0
//   colsum  f32 [9600]   @ 38400
//   colmax  u32 [9600]   @ 76800
//   rowpack u64 [9600]   @ 115200   (8-aligned)
// total 192000 bytes

__global__ __launch_bounds__(256) void k_init(unsigned* ws) {
    int i = blockIdx.x * 256 + threadIdx.x;
    if (i < 48000) ws[i] = 0u;
}

// Pass 1: sim GEMM -> e = exp(sim) stored into conf buffer; atomic row/col sums of e.
__global__ __launch_bounds__(256) void k_gemm(const float* __restrict__ f0,
                                              const float* __restrict__ f1,
                                              float* __restrict__ econf,
                                              float* __restrict__ rowsum,
                                              float* __restrict__ colsum) {
    const int n  = blockIdx.z;
    const int l0 = blockIdx.y * 96;
    const int s0 = blockIdx.x * 96;

    __shared__ __align__(16) _Float16 As[96][40];  // +8 pad: stride 80B breaks bank aliasing
    __shared__ __align__(16) _Float16 Bs[96][40];

    const int tid  = threadIdx.x;
    const int lane = tid & 63;
    const int w    = tid >> 6;       // 4 waves, 2x2
    const int wr   = w >> 1, wc = w & 1;
    const int q    = lane >> 4, r16 = lane & 15;

    f32x4 acc[3][3] = {};

    const float* A = f0 + ((size_t)n * L_DIM + l0) * C_DIM;
    const float* B = f1 + ((size_t)n * L_DIM + s0) * C_DIM;

    for (int k0 = 0; k0 < C_DIM; k0 += 32) {
        __syncthreads();
        // stage 96x32 f32 -> f16 for A and B  (768 float4 each / 256 threads = 3 each)
#pragma unroll
        for (int i = 0; i < 3; ++i) {
            int idx = tid + i * 256;
            int row = idx >> 3;        // 0..95
            int c4  = idx & 7;         // float4 within 32 cols
            float4 va = *(const float4*)(A + (size_t)row * C_DIM + k0 + c4 * 4);
            float4 vb = *(const float4*)(B + (size_t)row * C_DIM + k0 + c4 * 4);
            f16x4 ha = { (_Float16)va.x, (_Float16)va.y, (_Float16)va.z, (_Float16)va.w };
            f16x4 hb = { (_Float16)vb.x, (_Float16)vb.y, (_Float16)vb.z, (_Float16)vb.w };
            *(f16x4*)(&As[row][c4 * 4]) = ha;
            *(f16x4*)(&Bs[row][c4 * 4]) = hb;
        }
        __syncthreads();

        f16x8 af[3], bf[3];
#pragma unroll
        for (int m = 0; m < 3; ++m)
            af[m] = *(const f16x8*)(&As[wr * 48 + m * 16 + r16][q * 8]);
#pragma unroll
        for (int nn = 0; nn < 3; ++nn)
            bf[nn] = *(const f16x8*)(&Bs[wc * 48 + nn * 16 + r16][q * 8]);

#pragma unroll
        for (int m = 0; m < 3; ++m)
#pragma unroll
            for (int nn = 0; nn < 3; ++nn)
                acc[m][nn] = __builtin_amdgcn_mfma_f32_16x16x32_f16(af[m], bf[nn], acc[m][nn], 0, 0, 0);
    }

    // Epilogue: e = exp(sim), write, accumulate row/col partial sums.
    const float SIM_SCALE = 0.0390625f;  // (1/sqrt(256))^2 / 0.1
    float rp[3][4];  // per (m, reg): sum over this lane's 3 cols
    float cp[3] = {0.f, 0.f, 0.f};  // per nn: sum over this lane's 12 rows
    const size_t base = (size_t)n * L_DIM * L_DIM;

#pragma unroll
    for (int m = 0; m < 3; ++m) {
#pragma unroll
        for (int reg = 0; reg < 4; ++reg) {
            int grow = l0 + wr * 48 + m * 16 + q * 4 + reg;
            size_t rowoff = base + (size_t)grow * L_DIM;
            float rsum = 0.f;
#pragma unroll
            for (int nn = 0; nn < 3; ++nn) {
                int gcol = s0 + wc * 48 + nn * 16 + r16;
                float e = __expf(acc[m][nn][reg] * SIM_SCALE);
                econf[rowoff + gcol] = e;
                rsum += e;
                cp[nn] += e;
            }
            rp[m][reg] = rsum;
        }
    }

    // rowsum: reduce over the 16 lanes sharing a row set (xor 1,2,4,8 keeps q fixed)
#pragma unroll
    for (int m = 0; m < 3; ++m)
#pragma unroll
        for (int reg = 0; reg < 4; ++reg) {
            float v = rp[m][reg];
            v += __shfl_xor(v, 1);
            v += __shfl_xor(v, 2);
            v += __shfl_xor(v, 4);
            v += __shfl_xor(v, 8);
            if (r16 == 0)
                atomicAdd(&rowsum[n * L_DIM + l0 + wr * 48 + m * 16 + q * 4 + reg], v);
        }
    // colsum: reduce over the 4 q-groups (xor 16,32 keeps r16 fixed)
#pragma unroll
    for (int nn = 0; nn < 3; ++nn) {
        float v = cp[nn];
        v += __shfl_xor(v, 16);
        v += __shfl_xor(v, 32);
        if (q == 0)
            atomicAdd(&colsum[n * L_DIM + s0 + wc * 48 + nn * 16 + r16], v);
    }
}

// Pass 2: conf = e*e*invC*invR in place; track row (max,argmax) and col max.
__global__ __launch_bounds__(256) void k_norm(float* __restrict__ conf,
                                              const float* __restrict__ rowsum,
                                              const float* __restrict__ colsum,
                                              unsigned* __restrict__ colmax,
                                              unsigned long long* __restrict__ rowpack) {
    const int nr0 = blockIdx.y * 64;          // 150 blocks of 64 rows (no n straddle: 4800%64? 4800/64=75 exact)
    const int n   = nr0 / L_DIM;
    const int c   = blockIdx.x * 1024 + threadIdx.x * 4;
    const bool valid = (c < L_DIM);

    f32x4 invC = {0.f, 0.f, 0.f, 0.f};
    if (valid) {
        f32x4 cs = *(const f32x4*)(&colsum[n * L_DIM + c]);
        invC[0] = 1.f / cs[0]; invC[1] = 1.f / cs[1];
        invC[2] = 1.f / cs[2]; invC[3] = 1.f / cs[3];
    }
    f32x4 cmax = {0.f, 0.f, 0.f, 0.f};

    __shared__ unsigned long long red[4];
    const int lane = threadIdx.x & 63;
    const int w    = threadIdx.x >> 6;

    for (int r = 0; r < 64; ++r) {
        const int nr = nr0 + r;
        const float invR = 1.f / rowsum[nr];
        unsigned long long pack = 0ull;
        if (valid) {
            size_t off = (size_t)nr * L_DIM + c;
            f32x4 e = *(f32x4*)(conf + off);
            f32x4 cf;
#pragma unroll
            for (int j = 0; j < 4; ++j) cf[j] = e[j] * e[j] * invC[j] * invR;
            *(f32x4*)(conf + off) = cf;
#pragma unroll
            for (int j = 0; j < 4; ++j) cmax[j] = fmaxf(cmax[j], cf[j]);
            float bv = cf[0]; int bc = c;
#pragma unroll
            for (int j = 1; j < 4; ++j) if (cf[j] > bv) { bv = cf[j]; bc = c + j; }
            pack = ((unsigned long long)__float_as_uint(bv) << 32) |
                   (unsigned long long)(0xFFFFFFFFu - (unsigned)bc);
        }
#pragma unroll
        for (int m = 1; m < 64; m <<= 1) {
            unsigned long long o = __shfl_xor(pack, m);
            if (o > pack) pack = o;
        }
        if (lane == 0) red[w] = pack;
        __syncthreads();
        if (threadIdx.x == 0) {
            unsigned long long p = red[0];
#pragma unroll
            for (int i = 1; i < 4; ++i) if (red[i] > p) p = red[i];
            atomicMax(&rowpack[nr], p);
        }
        __syncthreads();
    }
    if (valid) {
#pragma unroll
        for (int j = 0; j < 4; ++j)
            atomicMax(&colmax[n * L_DIM + c + j], __float_as_uint(cmax[j]));
    }
}

// Pass 3: mutual-NN + threshold + border -> mask_v, j_ids, mconf.
__global__ __launch_bounds__(256) void k_match(const unsigned long long* __restrict__ rowpack,
                                               const unsigned* __restrict__ colmax,
                                               float* __restrict__ out) {
    int i = blockIdx.x * 256 + threadIdx.x;
    if (i >= 2 * L_DIM) return;
    int n = i / L_DIM, l = i % L_DIM;
    unsigned long long p = rowpack[i];
    float v = __uint_as_float((unsigned)(p >> 32));
    int cand = (int)(0xFFFFFFFFu - (unsigned)(p & 0xFFFFFFFFull));
    if (cand < 0 || cand >= L_DIM) cand = 0;
    int h0 = l / 80, w0 = l % 80;
    int h1 = cand / 80, w1 = cand % 80;
    bool bm0 = (h0 >= 2) && (h0 < 58) && (w0 >= 2) && (w0 < 78);
    bool bm1 = (h1 >= 2) && (h1 < 58) && (w1 >= 2) && (w1 < 78);
    float cm = __uint_as_float(colmax[n * L_DIM + cand]);
    bool mask = (v > 0.2f) && bm0 && bm1 && (v == cm);
    out[CONF_ELEMS + i]            = mask ? 1.0f : 0.0f;        // mask_v
    out[CONF_ELEMS + 9600 + i]     = mask ? (float)cand : 0.0f; // j_ids
    out[CONF_ELEMS + 19200 + i]    = mask ? v : 0.0f;           // mconf
}

extern "C" void kernel_launch(void* const* d_in, const int* in_sizes, int n_in,
                              void* d_out, int out_size, void* d_ws, size_t ws_size,
                              hipStream_t stream) {
    const float* f0 = (const float*)d_in[0];
    const float* f1 = (const float*)d_in[1];
    float* out = (float*)d_out;

    float* rowsum = (float*)d_ws;
    float* colsum = rowsum + 9600;
    unsigned* colmax = (unsigned*)(colsum + 9600);
    unsigned long long* rowpack = (unsigned long long*)((char*)d_ws + 115200);

    k_init<<<dim3((48000 + 255) / 256), 256, 0, stream>>>((unsigned*)d_ws);
    k_gemm<<<dim3(50, 50, 2), 256, 0, stream>>>(f0, f1, out, rowsum, colsum);
    k_norm<<<dim3(5, 150), 256, 0, stream>>>(out, rowsum, colsum, colmax, rowpack);
    k_match<<<dim3((2 * L_DIM + 255) / 256), 256, 0, stream>>>(rowpack, colmax, out);
}

// Round 2
// 192.113 us; speedup vs baseline: 1.0664x; 1.0664x over previous
//
#include <hip/hip_runtime.h>
#include <hip/hip_bf16.h>
#include <cstdint>

#define L_DIM 4800
#define C_DIM 256
#define CONF_ELEMS ((size_t)2 * L_DIM * L_DIM)

typedef _Float16 f16x8 __attribute__((ext_vector_type(8)));
typedef float f32x4 __attribute__((ext_vector_type(4)));

typedef const __attribute__((address_space(1))) uint32_t glb_u32;
typedef __attribute__((address_space(3))) uint32_t lds_u32;

// ws layout (bytes):
//   rowsum  f32 [9600]   @ 0        (pass A: sums; after k_inv: 1/sum)
//   colsum  f32 [9600]   @ 38400
//   colmax  u32 [9600]   @ 76800
//   rowpack u64 [9600]   @ 115200
//   h0 f16 [2*4800*256]  @ 192000   (optional, if ws_size permits)
//   h1 f16 [2*4800*256]  @ 5107200  -> end 10022400

__global__ __launch_bounds__(256) void k_init(unsigned* ws) {
    int i = blockIdx.x * 256 + threadIdx.x;
    if (i < 48000) ws[i] = 0u;
}

__global__ __launch_bounds__(256) void k_cvt(const float* __restrict__ src,
                                             _Float16* __restrict__ dst) {
    int i = blockIdx.x * 256 + threadIdx.x;   // 307200 threads, 8 floats each
    const float4* s4 = (const float4*)src;
    float4 a = s4[i * 2], b = s4[i * 2 + 1];
    f16x8 h = { (_Float16)a.x, (_Float16)a.y, (_Float16)a.z, (_Float16)a.w,
                (_Float16)b.x, (_Float16)b.y, (_Float16)b.z, (_Float16)b.w };
    *(f16x8*)(dst + (size_t)i * 8) = h;
}

__global__ __launch_bounds__(256) void k_inv(float* p) {
    int i = blockIdx.x * 256 + threadIdx.x;
    if (i < 19200) p[i] = 1.0f / p[i];
}

// 96x96 tile GEMM, BK=64, 4 waves (2x2), wave tile 48x48 (3x3 frags of 16x16x32 f16).
// LDS layout per matrix: [96 rows][8 chunks of 16B], chunk slot kc8 holds global
// k-chunk (kc8 ^ (row&7))  -- both-sides XOR swizzle (T2 via pre-swizzled source).
template<bool F16SRC, bool FINAL>
__global__ __launch_bounds__(256) void k_gemm2(const void* __restrict__ srcA,
                                               const void* __restrict__ srcB,
                                               float* __restrict__ conf,
                                               float* __restrict__ rowsum,
                                               float* __restrict__ colsum,
                                               unsigned* __restrict__ colmax,
                                               unsigned long long* __restrict__ rowpack) {
    const int n  = blockIdx.z;
    const int l0 = blockIdx.y * 96;
    const int s0 = blockIdx.x * 96;

    __shared__ __align__(16) _Float16 As[96 * 64];
    __shared__ __align__(16) _Float16 Bs[96 * 64];

    const int tid  = threadIdx.x;
    const int lane = tid & 63;
    const int w    = tid >> 6;
    const int wr   = w >> 1, wc = w & 1;
    const int q    = lane >> 4, r16 = lane & 15;

    f32x4 acc[3][3] = {};

    for (int t = 0; t < 4; ++t) {
        const int k0 = t * 64;
        __syncthreads();   // LDS reads of previous iter complete before overwrite
        if constexpr (F16SRC) {
            const _Float16* A = (const _Float16*)srcA + ((size_t)n * L_DIM + l0) * C_DIM;
            const _Float16* B = (const _Float16*)srcB + ((size_t)n * L_DIM + s0) * C_DIM;
#pragma unroll
            for (int i = 0; i < 3; ++i) {
                int c   = tid + i * 256;
                int row = c >> 3;
                int kc  = (c & 7) ^ (row & 7);    // pre-swizzled global source
                __builtin_amdgcn_global_load_lds(
                    (glb_u32*)(A + (size_t)row * C_DIM + k0 + kc * 8),
                    (lds_u32*)(As + (i * 256 + w * 64) * 8), 16, 0, 0);
                __builtin_amdgcn_global_load_lds(
                    (glb_u32*)(B + (size_t)row * C_DIM + k0 + kc * 8),
                    (lds_u32*)(Bs + (i * 256 + w * 64) * 8), 16, 0, 0);
            }
        } else {
            const float* A = (const float*)srcA + ((size_t)n * L_DIM + l0) * C_DIM;
            const float* B = (const float*)srcB + ((size_t)n * L_DIM + s0) * C_DIM;
#pragma unroll
            for (int i = 0; i < 3; ++i) {
                int c   = tid + i * 256;
                int row = c >> 3;
                int kc  = (c & 7) ^ (row & 7);
                const float* pa = A + (size_t)row * C_DIM + k0 + kc * 8;
                const float* pb = B + (size_t)row * C_DIM + k0 + kc * 8;
                float4 a0 = ((const float4*)pa)[0], a1 = ((const float4*)pa)[1];
                float4 b0 = ((const float4*)pb)[0], b1 = ((const float4*)pb)[1];
                f16x8 ha = { (_Float16)a0.x, (_Float16)a0.y, (_Float16)a0.z, (_Float16)a0.w,
                             (_Float16)a1.x, (_Float16)a1.y, (_Float16)a1.z, (_Float16)a1.w };
                f16x8 hb = { (_Float16)b0.x, (_Float16)b0.y, (_Float16)b0.z, (_Float16)b0.w,
                             (_Float16)b1.x, (_Float16)b1.y, (_Float16)b1.z, (_Float16)b1.w };
                *(f16x8*)(As + (size_t)c * 8) = ha;
                *(f16x8*)(Bs + (size_t)c * 8) = hb;
            }
        }
        __syncthreads();   // drains vmcnt(0): global_load_lds complete

        f16x8 af[2][3], bf[2][3];
#pragma unroll
        for (int m = 0; m < 3; ++m) {
            int row = wr * 48 + m * 16 + r16;
#pragma unroll
            for (int ks = 0; ks < 2; ++ks)
                af[ks][m] = *(const f16x8*)(As + row * 64 + (((ks * 4 + q) ^ (row & 7)) * 8));
        }
#pragma unroll
        for (int nn = 0; nn < 3; ++nn) {
            int row = wc * 48 + nn * 16 + r16;
#pragma unroll
            for (int ks = 0; ks < 2; ++ks)
                bf[ks][nn] = *(const f16x8*)(Bs + row * 64 + (((ks * 4 + q) ^ (row & 7)) * 8));
        }
#pragma unroll
        for (int ks = 0; ks < 2; ++ks)
#pragma unroll
            for (int m = 0; m < 3; ++m)
#pragma unroll
                for (int nn = 0; nn < 3; ++nn)
                    acc[m][nn] = __builtin_amdgcn_mfma_f32_16x16x32_f16(af[ks][m], bf[ks][nn], acc[m][nn], 0, 0, 0);
    }

    const float SIM_SCALE = 0.0390625f;  // (1/sqrt(C))^2 / TEMPERATURE

    if constexpr (!FINAL) {
        // Pass A: accumulate row/col sums of e = exp(sim)
        float cp[3] = {0.f, 0.f, 0.f};
#pragma unroll
        for (int m = 0; m < 3; ++m) {
#pragma unroll
            for (int reg = 0; reg < 4; ++reg) {
                float rsum = 0.f;
#pragma unroll
                for (int nn = 0; nn < 3; ++nn) {
                    float e = __expf(acc[m][nn][reg] * SIM_SCALE);
                    rsum += e;
                    cp[nn] += e;
                }
                rsum += __shfl_xor(rsum, 1);
                rsum += __shfl_xor(rsum, 2);
                rsum += __shfl_xor(rsum, 4);
                rsum += __shfl_xor(rsum, 8);
                if (r16 == 0)
                    atomicAdd(&rowsum[n * L_DIM + l0 + wr * 48 + m * 16 + q * 4 + reg], rsum);
            }
        }
#pragma unroll
        for (int nn = 0; nn < 3; ++nn) {
            float v = cp[nn];
            v += __shfl_xor(v, 16);
            v += __shfl_xor(v, 32);
            if (q == 0)
                atomicAdd(&colsum[n * L_DIM + s0 + wc * 48 + nn * 16 + r16], v);
        }
    } else {
        // Pass B: conf = exp(2*sim)*invR*invC -> write; fused row argmax / col max
        const size_t base = (size_t)n * L_DIM * L_DIM;
        float ivC[3];
#pragma unroll
        for (int nn = 0; nn < 3; ++nn)
            ivC[nn] = colsum[n * L_DIM + s0 + wc * 48 + nn * 16 + r16];
        float cmx[3] = {0.f, 0.f, 0.f};
#pragma unroll
        for (int m = 0; m < 3; ++m) {
#pragma unroll
            for (int reg = 0; reg < 4; ++reg) {
                const int grow = l0 + wr * 48 + m * 16 + q * 4 + reg;
                const float ivR = rowsum[n * L_DIM + grow];   // inverted by k_inv
                const size_t rowoff = base + (size_t)grow * L_DIM;
                float bv = -1.f; int bc = 0;
#pragma unroll
                for (int nn = 0; nn < 3; ++nn) {
                    const int gcol = s0 + wc * 48 + nn * 16 + r16;
                    float cf = __expf(acc[m][nn][reg] * (2.0f * SIM_SCALE)) * ivR * ivC[nn];
                    conf[rowoff + gcol] = cf;
                    cmx[nn] = fmaxf(cmx[nn], cf);
                    if (cf > bv) { bv = cf; bc = gcol; }
                }
                unsigned long long pack =
                    ((unsigned long long)__float_as_uint(bv) << 32) |
                    (unsigned long long)(0xFFFFFFFFu - (unsigned)bc);
#pragma unroll
                for (int d = 1; d < 16; d <<= 1) {
                    unsigned long long o = __shfl_xor(pack, d);
                    if (o > pack) pack = o;
                }
                if (r16 == 0)
                    atomicMax(&rowpack[n * L_DIM + grow], pack);
            }
        }
#pragma unroll
        for (int nn = 0; nn < 3; ++nn) {
            float v = cmx[nn];
            v = fmaxf(v, __shfl_xor(v, 16));
            v = fmaxf(v, __shfl_xor(v, 32));
            if (q == 0)
                atomicMax(&colmax[n * L_DIM + s0 + wc * 48 + nn * 16 + r16], __float_as_uint(v));
        }
    }
}

__global__ __launch_bounds__(256) void k_match(const unsigned long long* __restrict__ rowpack,
                                               const unsigned* __restrict__ colmax,
                                               float* __restrict__ out) {
    int i = blockIdx.x * 256 + threadIdx.x;
    if (i >= 2 * L_DIM) return;
    int n = i / L_DIM, l = i % L_DIM;
    unsigned long long p = rowpack[i];
    float v = __uint_as_float((unsigned)(p >> 32));
    int cand = (int)(0xFFFFFFFFu - (unsigned)(p & 0xFFFFFFFFull));
    if (cand < 0 || cand >= L_DIM) cand = 0;
    int h0 = l / 80, w0 = l % 80;
    int h1 = cand / 80, w1 = cand % 80;
    bool bm0 = (h0 >= 2) && (h0 < 58) && (w0 >= 2) && (w0 < 78);
    bool bm1 = (h1 >= 2) && (h1 < 58) && (w1 >= 2) && (w1 < 78);
    float cm = __uint_as_float(colmax[n * L_DIM + cand]);
    bool mask = (v > 0.2f) && bm0 && bm1 && (v == cm);
    out[CONF_ELEMS + i]         = mask ? 1.0f : 0.0f;        // mask_v
    out[CONF_ELEMS + 9600 + i]  = mask ? (float)cand : 0.0f; // j_ids
    out[CONF_ELEMS + 19200 + i] = mask ? v : 0.0f;           // mconf
}

extern "C" void kernel_launch(void* const* d_in, const int* in_sizes, int n_in,
                              void* d_out, int out_size, void* d_ws, size_t ws_size,
                              hipStream_t stream) {
    const float* f0 = (const float*)d_in[0];
    const float* f1 = (const float*)d_in[1];
    float* out = (float*)d_out;

    float* rowsum = (float*)d_ws;
    float* colsum = rowsum + 9600;
    unsigned* colmax = (unsigned*)(colsum + 9600);
    unsigned long long* rowpack = (unsigned long long*)((char*)d_ws + 115200);
    _Float16* h0 = (_Float16*)((char*)d_ws + 192000);
    _Float16* h1 = h0 + (size_t)2 * L_DIM * C_DIM;

    const bool usef16 = ws_size >= 10022400;

    k_init<<<dim3(188), 256, 0, stream>>>((unsigned*)d_ws);

    if (usef16) {
        k_cvt<<<dim3(1200), 256, 0, stream>>>(f0, h0);
        k_cvt<<<dim3(1200), 256, 0, stream>>>(f1, h1);
        k_gemm2<true, false><<<dim3(50, 50, 2), 256, 0, stream>>>(
            h0, h1, out, rowsum, colsum, colmax, rowpack);
        k_inv<<<dim3(75), 256, 0, stream>>>(rowsum);
        k_gemm2<true, true><<<dim3(50, 50, 2), 256, 0, stream>>>(
            h0, h1, out, rowsum, colsum, colmax, rowpack);
    } else {
        k_gemm2<false, false><<<dim3(50, 50, 2), 256, 0, stream>>>(
            f0, f1, out, rowsum, colsum, colmax, rowpack);
        k_inv<<<dim3(75), 256, 0, stream>>>(rowsum);
        k_gemm2<false, true><<<dim3(50, 50, 2), 256, 0, stream>>>(
            f0, f1, out, rowsum, colsum, colmax, rowpack);
    }
    k_match<<<dim3(38), 256, 0, stream>>>(rowpack, colmax, out);
}